// Round 13
// baseline (1538.315 us; speedup 1.0000x reference)
//
#include <hip/hip_runtime.h>
#include <math.h>

#define N_NODES 100000
#define N_EDGES 3200000
#define NPB 256                              // nodes per bucket (CSR build)
#define NBUCK ((N_NODES + NPB - 1) / NPB)    // 391
#define NPW 4                                // nodes per wave (fused kernels)

typedef unsigned short ushort_t;

static __device__ __forceinline__ float bf2f(ushort_t u) {
    return __uint_as_float(((unsigned int)u) << 16);
}
static __device__ __forceinline__ unsigned int f2bf_u(float f) {
    unsigned int x = __float_as_uint(f);
    unsigned int lsb = (x >> 16) & 1u;
    x += 0x7fffu + lsb;  // round-to-nearest-even
    return x >> 16;
}
static __device__ __forceinline__ ushort_t f2bf(float f) { return (ushort_t)f2bf_u(f); }

// ---- pass A: bucket histogram (LDS-aggregated) ----
__global__ void bucket_hist_kernel(const int* __restrict__ col, int* __restrict__ bucketCnt) {
    __shared__ int h[NBUCK];
    for (int t = threadIdx.x; t < NBUCK; t += 256) h[t] = 0;
    __syncthreads();
    for (int e = blockIdx.x * 256 + threadIdx.x; e < N_EDGES; e += gridDim.x * 256)
        atomicAdd(&h[col[e] >> 8], 1);
    __syncthreads();
    for (int t = threadIdx.x; t < NBUCK; t += 256)
        if (h[t]) atomicAdd(&bucketCnt[t], h[t]);
}

// ---- pass B: scan bucket counts -> bucketOff; init bcursor ----
__global__ void bucket_scan_kernel(const int* __restrict__ bucketCnt, int* __restrict__ bucketOff,
                                   int* __restrict__ bcursor) {
    __shared__ int tmp[512];
    int tx = threadIdx.x;
    int v = (tx < NBUCK) ? bucketCnt[tx] : 0;
    tmp[tx] = v;
    __syncthreads();
    for (int off = 1; off < 512; off <<= 1) {
        int t = (tx >= off) ? tmp[tx - off] : 0;
        __syncthreads();
        if (tx >= off) tmp[tx] += t;
        __syncthreads();
    }
    if (tx < NBUCK) {
        int o = tmp[tx] - v;
        bucketOff[tx] = o;
        bcursor[tx] = o;
    }
}

// ---- pass C: bin edges by bucket (block-aggregated append) ----
__global__ void bin_kernel(const int* __restrict__ row, const int* __restrict__ col,
                           int* __restrict__ bcursor, int2* __restrict__ tmpE) {
    __shared__ int hist[NBUCK];
    __shared__ int chunkOff[NBUCK];
    int tx = threadIdx.x;
    for (int t = tx; t < NBUCK; t += 512) hist[t] = 0;
    __syncthreads();
    int base = blockIdx.x * 4096;
    int myc[8], myr[8], myrank[8];
#pragma unroll 8
    for (int k = 0; k < 8; ++k) {
        int idx = base + k * 512 + tx;
        bool valid = idx < N_EDGES;
        int c = valid ? col[idx] : 0;
        int r = valid ? row[idx] : 0;
        myc[k] = c;
        myr[k] = r;
        myrank[k] = valid ? atomicAdd(&hist[c >> 8], 1) : 0;
    }
    __syncthreads();
    for (int t = tx; t < NBUCK; t += 512) {
        int hv = hist[t];
        chunkOff[t] = hv ? atomicAdd(&bcursor[t], hv) : 0;
    }
    __syncthreads();
#pragma unroll 8
    for (int k = 0; k < 8; ++k) {
        int idx = base + k * 512 + tx;
        if (idx < N_EDGES) {
            int pos = chunkOff[myc[k] >> 8] + myrank[k];
            tmpE[pos] = make_int2(myr[k], myc[k]);
        }
    }
}

// ---- pass D: per-bucket CSR: starts, isq, edgeRow; + npos reduction ----
__global__ void csr_kernel(const int2* __restrict__ tmpE, const int* __restrict__ bucketOff,
                           const int* __restrict__ bucketCnt, int* __restrict__ starts,
                           int* __restrict__ edgeRow, float* __restrict__ isq,
                           const float* __restrict__ labels, float* __restrict__ npos) {
    __shared__ int scnt[NPB];
    __shared__ int sscan[NPB];
    __shared__ int scur[NPB];
    __shared__ float red[NPB];
    int b = blockIdx.x;
    int lo = b * NPB;
    int nn = N_NODES - lo;
    if (nn > NPB) nn = NPB;
    int base = bucketOff[b];
    int ecnt = bucketCnt[b];
    int tx = threadIdx.x;
    scnt[tx] = 0;
    __syncthreads();
    for (int t = tx; t < ecnt; t += NPB) atomicAdd(&scnt[tmpE[base + t].y - lo], 1);
    __syncthreads();
    int v = scnt[tx];
    sscan[tx] = v;
    __syncthreads();
    for (int off = 1; off < NPB; off <<= 1) {
        int t = (tx >= off) ? sscan[tx - off] : 0;
        __syncthreads();
        if (tx >= off) sscan[tx] += t;
        __syncthreads();
    }
    int excl = sscan[tx] - v;
    scur[tx] = excl;
    float lab = 0.0f;
    if (tx < nn) {
        starts[lo + tx] = base + excl;
        isq[lo + tx] = rsqrtf((float)v + 1.0f);
        lab = labels[lo + tx];
    }
    if (b == NBUCK - 1 && tx == 0) starts[N_NODES] = N_EDGES;
    red[tx] = lab;
    __syncthreads();
    for (int s = NPB / 2; s > 0; s >>= 1) {
        if (tx < s) red[tx] += red[tx + s];
        __syncthreads();
    }
    if (tx == 0) atomicAdd(npos, red[0]);
    for (int t = tx; t < ecnt; t += NPB) {
        int2 rc = tmpE[base + t];
        int p = atomicAdd(&scur[rc.y - lo], 1);
        edgeRow[base + p] = rc.x;
    }
}

// ---- x (fp32 N*32) -> bf16 table PRE-SCALED by isq[node] (normal layout) ----
__global__ void xcast_kernel(const float* __restrict__ x, const float* __restrict__ isq,
                             ushort_t* __restrict__ xs) {
    int i = blockIdx.x * 256 + threadIdx.x;  // group of 4 floats; node = i>>3
    if (i < (N_NODES * 32) / 4) {
        float s = isq[i >> 3];
        float4 v = ((const float4*)x)[i];
        ushort4 o;
        o.x = f2bf(v.x * s); o.y = f2bf(v.y * s); o.z = f2bf(v.z * s); o.w = f2bf(v.w * s);
        ((ushort4*)xs)[i] = o;
    }
}

// ---- pack W1/W2/W3 into per-lane bf16x2 column tables ----
__global__ void wpack_kernel(const float* __restrict__ W1, const float* __restrict__ W2,
                             const float* __restrict__ W3, unsigned int* __restrict__ wp) {
    int t = blockIdx.x * 256 + threadIdx.x;
    if (t >= 80 * 64) return;
    int k2 = t >> 6, l = t & 63;
    const float* W;
    int kk;
    if (k2 < 16) { W = W1; kk = k2; }
    else if (k2 < 48) { W = W2; kk = k2 - 16; }
    else { W = W3; kk = k2 - 48; }
    float lo = W[(2 * kk) * 64 + l];
    float hi = W[(2 * kk + 1) * 64 + l];
    wp[t] = (f2bf_u(hi) << 16) | f2bf_u(lo);
}

// ---- layer 1 fused: agg(xs)[32] -> @W1+b -> relu -> h1 written SLICED+SCALED ----
__global__ void fused32_kernel(const int* __restrict__ starts, const int* __restrict__ edgeRow,
                               const ushort_t* __restrict__ xs, const float* __restrict__ isq,
                               const unsigned int* __restrict__ wpG,
                               const float* __restrict__ bias, ushort_t* __restrict__ hsl) {
    __shared__ float sAgg[4][32];
    int w = threadIdx.x >> 6;
    int lane = threadIdx.x & 63;
    int f = lane & 31, half = lane >> 5;
    unsigned int wpk[16];
#pragma unroll
    for (int k2 = 0; k2 < 16; ++k2) wpk[k2] = wpG[k2 * 64 + lane];
    float bias_r = bias[lane];
    int nodeBase = blockIdx.x * (4 * NPW) + w * NPW;
    for (int i = 0; i < NPW; ++i) {
        int node = __builtin_amdgcn_readfirstlane(nodeBase + i);
        int sU = starts[node];
        int eU = starts[node + 1];
        float sic = isq[node];
        float acc[4] = {0.0f, 0.0f, 0.0f, 0.0f};
        int ngrp = (eU - sU + 15) >> 4;
        int jb = sU;
        for (int g = 0; g < ngrp; ++g) {
            int rows[16];
#pragma unroll
            for (int q = 0; q < 16; ++q) rows[q] = edgeRow[jb + q];  // uniform -> s_load
            unsigned int vv[16];
#pragma unroll
            for (int q = 0; q < 16; ++q) vv[q] = xs[(rows[q] << 5) + f];
#pragma unroll
            for (int q = 0; q < 16; ++q) {
                float n = (jb + q < eU) ? 1.0f : 0.0f;
                acc[q & 3] = fmaf(bf2f((ushort_t)vv[q]), n, acc[q & 3]);
            }
            jb += 16;
        }
        float accsum = (acc[0] + acc[1]) + (acc[2] + acc[3]);  // halves identical
        if (half == 0) {
            accsum += bf2f(xs[(node << 5) + f]);  // self-loop (isq folded in xs)
            sAgg[w][f] = accsum * sic;
        }
        float o = bias_r;
#pragma unroll
        for (int q = 0; q < 8; ++q) {
            float4 av = *(const float4*)&sAgg[w][q * 4];
            unsigned int p0 = wpk[2 * q], p1 = wpk[2 * q + 1];
            o = fmaf(av.x, __uint_as_float(p0 << 16), o);
            o = fmaf(av.y, __uint_as_float(p0 & 0xffff0000u), o);
            o = fmaf(av.z, __uint_as_float(p1 << 16), o);
            o = fmaf(av.w, __uint_as_float(p1 & 0xffff0000u), o);
        }
        o = o > 0.0f ? o : 0.0f;
        // sliced store: slab = lane>>4 (features 16p..16p+15), scaled by isq[node]
        hsl[((lane >> 4) * N_NODES + node) * 16 + (lane & 15)] = f2bf(o * sic);
    }
}

// ---- agg pass: 16 features from an L2-resident 3.2MB slab; 4 edges/instr ----
__global__ void agg16_kernel(const int* __restrict__ starts, const int* __restrict__ edgeRow,
                             const ushort_t* __restrict__ slab, const float* __restrict__ isq,
                             float* __restrict__ aggOut, int foff) {
    int tid = threadIdx.x;
    int w = tid >> 6;
    int lane = tid & 63;
    int j = lane & 15;
    int lq = lane >> 4;                 // edge sub-slot 0..3
    bool q1 = (lane & 16) != 0;
    bool q2 = (lane & 32) != 0;
    int nodeBase = blockIdx.x * (4 * NPW) + w * NPW;
    for (int i = 0; i < NPW; ++i) {
        int node = __builtin_amdgcn_readfirstlane(nodeBase + i);
        int sU = starts[node];
        int eU = starts[node + 1];
        float sic = isq[node];
        float acc = 0.0f, acc2 = 0.0f;
        int ngrp = (eU - sU + 15) >> 4;
        int jb = sU;
        for (int g = 0; g < ngrp; ++g) {
            int rows[16];
#pragma unroll
            for (int q = 0; q < 16; ++q) rows[q] = edgeRow[jb + q];  // uniform -> s_load
#pragma unroll
            for (int b = 0; b < 4; ++b) {   // 4 edges per vmem instr (quarter-wave each)
                int r01 = q1 ? rows[4 * b + 1] : rows[4 * b + 0];
                int r23 = q1 ? rows[4 * b + 3] : rows[4 * b + 2];
                int r = q2 ? r23 : r01;
                int eidx = jb + 4 * b + lq;
                float nv = (eidx < eU) ? 1.0f : 0.0f;
                float v = bf2f(slab[(r << 4) + j]);
                if (b & 1) acc2 = fmaf(v, nv, acc2);
                else       acc  = fmaf(v, nv, acc);
            }
            jb += 16;
        }
        acc += acc2;
        acc += __shfl_xor(acc, 16);      // sum the 4 edge-quarters
        acc += __shfl_xor(acc, 32);
        acc += bf2f(slab[(node << 4) + j]);  // self-loop (scaled table)
        acc *= sic;
        if (lane < 16) aggOut[(node << 6) + foff + j] = acc;
    }
}

// ---- dense epilogue: agg[64] @ W + b -> relu -> bf16 (sliced-scaled or normal) ----
__global__ void gemm64_kernel(const float* __restrict__ agg, const unsigned int* __restrict__ wpG,
                              const float* __restrict__ bias, const float* __restrict__ isq,
                              ushort_t* __restrict__ outp, int sliced) {
    __shared__ float sAgg[4][64];
    int w = threadIdx.x >> 6;
    int lane = threadIdx.x & 63;
    unsigned int wpk[32];
#pragma unroll
    for (int k2 = 0; k2 < 32; ++k2) wpk[k2] = wpG[(k2 << 6) + lane];
    float bias_r = bias[lane];
    int nodeBase = blockIdx.x * (4 * NPW) + w * NPW;
    for (int i = 0; i < NPW; ++i) {
        int node = nodeBase + i;
        sAgg[w][lane] = agg[(node << 6) + lane];  // coalesced; wave-synchronous reuse
        float o = bias_r;
#pragma unroll
        for (int q = 0; q < 16; ++q) {
            float4 av = *(const float4*)&sAgg[w][q * 4];
            unsigned int p0 = wpk[2 * q], p1 = wpk[2 * q + 1];
            o = fmaf(av.x, __uint_as_float(p0 << 16), o);
            o = fmaf(av.y, __uint_as_float(p0 & 0xffff0000u), o);
            o = fmaf(av.z, __uint_as_float(p1 << 16), o);
            o = fmaf(av.w, __uint_as_float(p1 & 0xffff0000u), o);
        }
        o = o > 0.0f ? o : 0.0f;
        if (sliced) {
            outp[((lane >> 4) * N_NODES + node) * 16 + (lane & 15)] = f2bf(o * isq[node]);
        } else {
            outp[(node << 6) + lane] = f2bf(o);
        }
    }
}

// ---- head: relu(h@Wl1+bl1)@Wl2+bl2 -> sigmoid -> p; weighted BCE -> loss ----
__global__ void head_kernel(const ushort_t* __restrict__ h, const float* __restrict__ Wl1,
                            const float* __restrict__ bl1, const float* __restrict__ Wl2,
                            const float* __restrict__ bl2, const float* __restrict__ labels,
                            const float* __restrict__ npos, float* __restrict__ out) {
    __shared__ float sW1[64 * 8];
    __shared__ float sb1[8];
    __shared__ float sW2[8];
    for (int t = threadIdx.x; t < 512; t += 256) sW1[t] = Wl1[t];
    if (threadIdx.x < 8) {
        sb1[threadIdx.x] = bl1[threadIdx.x];
        sW2[threadIdx.x] = Wl2[threadIdx.x];
    }
    __syncthreads();
    int i = blockIdx.x * 256 + threadIdx.x;
    float contrib = 0.0f;
    if (i < N_NODES) {
        const ushort4* hr4 = (const ushort4*)(h + (size_t)i * 64);
        float a[8];
#pragma unroll
        for (int j = 0; j < 8; ++j) a[j] = sb1[j];
#pragma unroll
        for (int kb = 0; kb < 16; ++kb) {
            ushort4 v4 = hr4[kb];
            float h0 = bf2f(v4.x), h1 = bf2f(v4.y), h2 = bf2f(v4.z), h3 = bf2f(v4.w);
#pragma unroll
            for (int j = 0; j < 8; ++j) {
                a[j] = fmaf(h0, sW1[(kb * 4 + 0) * 8 + j], a[j]);
                a[j] = fmaf(h1, sW1[(kb * 4 + 1) * 8 + j], a[j]);
                a[j] = fmaf(h2, sW1[(kb * 4 + 2) * 8 + j], a[j]);
                a[j] = fmaf(h3, sW1[(kb * 4 + 3) * 8 + j], a[j]);
            }
        }
        float z = bl2[0];
#pragma unroll
        for (int j = 0; j < 8; ++j) {
            float r = a[j] > 0.0f ? a[j] : 0.0f;
            z = fmaf(r, sW2[j], z);
        }
        float p = 1.0f / (1.0f + expf(-z));
        out[1 + i] = p;
        float y = labels[i];
        float np = *npos;
        float fn = (float)N_NODES;
        float wpos = fn / (2.0f * np);
        float wneg = fn / (2.0f * (fn - np));
        float wgt = y * wpos + (1.0f - y) * wneg;
        float lse = log1pf(expf(-fabsf(z)));
        float ls_pos = fminf(z, 0.0f) - lse;
        float ls_neg = fminf(-z, 0.0f) - lse;
        float bce = -(y * ls_pos + (1.0f - y) * ls_neg);
        contrib = wgt * bce / fn;
    }
    __shared__ float red[256];
    red[threadIdx.x] = contrib;
    __syncthreads();
    for (int s = 128; s > 0; s >>= 1) {
        if (threadIdx.x < s) red[threadIdx.x] += red[threadIdx.x + s];
        __syncthreads();
    }
    if (threadIdx.x == 0) atomicAdd(out, red[0]);
}

extern "C" void kernel_launch(void* const* d_in, const int* in_sizes, int n_in,
                              void* d_out, int out_size, void* d_ws, size_t ws_size,
                              hipStream_t stream) {
    const float* x      = (const float*)d_in[0];
    const int*   ei     = (const int*)d_in[1];
    const float* labels = (const float*)d_in[2];
    const float* W1  = (const float*)d_in[3];
    const float* b1  = (const float*)d_in[4];
    const float* W2  = (const float*)d_in[5];
    const float* b2  = (const float*)d_in[6];
    const float* W3  = (const float*)d_in[7];
    const float* b3  = (const float*)d_in[8];
    const float* Wl1 = (const float*)d_in[9];
    const float* bl1 = (const float*)d_in[10];
    const float* Wl2 = (const float*)d_in[11];
    const float* bl2 = (const float*)d_in[12];

    const int* row = ei;            // edge_index[0]
    const int* col = ei + N_EDGES;  // edge_index[1]
    float* out = (float*)d_out;

    // ---- workspace layout (tmpE aliased as fp32 agg buffer after csr) ----
    char* w = (char*)d_ws;
    int2*     tmpE    = (int2*)w;                               // E*8B
    float*    aggBuf  = (float*)w;                              // alias: N*64*4B (= E*8B)
    int*      edgeRow = (int*)(w + (size_t)N_EDGES * 8);        // (E+16)*4B (pad)
    ushort_t* xs      = (ushort_t*)(edgeRow + N_EDGES + 16);    // N*32*2B scaled
    ushort_t* hsl1    = xs + (size_t)N_NODES * 32;              // N*64*2B sliced scaled
    ushort_t* hsl2    = hsl1 + (size_t)N_NODES * 64;            // N*64*2B sliced scaled
    ushort_t* hbfF    = hsl2 + (size_t)N_NODES * 64;            // N*64*2B normal (head)
    int*      starts  = (int*)(hbfF + (size_t)N_NODES * 64);    // N+1
    int*      bucketCnt = starts + (N_NODES + 1);               // NBUCK
    int*      bucketOff = bucketCnt + NBUCK;                    // NBUCK
    int*      bcursor   = bucketOff + NBUCK;                    // NBUCK
    float*    isq  = (float*)(bcursor + NBUCK);                 // N
    float*    npos = isq + N_NODES;                             // 1
    unsigned int* wpG = (unsigned int*)(npos + 1);              // 80*64 u32

    hipMemsetAsync(bucketCnt, 0, NBUCK * sizeof(int), stream);
    hipMemsetAsync(npos, 0, sizeof(float), stream);
    hipMemsetAsync(out, 0, sizeof(float), stream);
    hipMemsetAsync(edgeRow + N_EDGES, 0, 16 * sizeof(int), stream);  // over-read slack

    const int FB = N_NODES / (4 * NPW);      // 6250
    const int BB = (N_EDGES + 4095) / 4096;  // 782
    const int XB = (N_NODES * 32 / 4 + 255) / 256;
    const int SLAB = N_NODES * 16;           // ushorts per feature slab

    bucket_hist_kernel<<<1024, 256, 0, stream>>>(col, bucketCnt);
    bucket_scan_kernel<<<1, 512, 0, stream>>>(bucketCnt, bucketOff, bcursor);
    bin_kernel<<<BB, 512, 0, stream>>>(row, col, bcursor, tmpE);
    csr_kernel<<<NBUCK, NPB, 0, stream>>>(tmpE, bucketOff, bucketCnt, starts, edgeRow, isq,
                                          labels, npos);
    xcast_kernel<<<XB, 256, 0, stream>>>(x, isq, xs);
    wpack_kernel<<<20, 256, 0, stream>>>(W1, W2, W3, wpG);

    // layer 1: gather x (normal layout) -> h1 sliced scaled
    fused32_kernel<<<FB, 256, 0, stream>>>(starts, edgeRow, xs, isq, wpG, b1, hsl1);

    // layer 2: 4 sliced agg passes (L2-resident 3.2MB slabs) + dense epilogue
    for (int p = 0; p < 4; ++p)
        agg16_kernel<<<FB, 256, 0, stream>>>(starts, edgeRow, hsl1 + (size_t)p * SLAB, isq,
                                             aggBuf, p * 16);
    gemm64_kernel<<<FB, 256, 0, stream>>>(aggBuf, wpG + 16 * 64, b2, isq, hsl2, 1);

    // layer 3
    for (int p = 0; p < 4; ++p)
        agg16_kernel<<<FB, 256, 0, stream>>>(starts, edgeRow, hsl2 + (size_t)p * SLAB, isq,
                                             aggBuf, p * 16);
    gemm64_kernel<<<FB, 256, 0, stream>>>(aggBuf, wpG + 48 * 64, b3, isq, hbfF, 0);

    head_kernel<<<(N_NODES + 255) / 256, 256, 0, stream>>>(hbfF, Wl1, bl1, Wl2, bl2, labels,
                                                           npos, out);
}

// Round 14
// 512.601 us; speedup vs baseline: 3.0010x; 3.0010x over previous
//
#include <hip/hip_runtime.h>
#include <math.h>

#define N_NODES 100000
#define N_EDGES 3200000
#define NPB 256                              // nodes per bucket
#define NBUCK ((N_NODES + NPB - 1) / NPB)    // 391
#define NPW 4                                // nodes per wave (fused kernels)

typedef unsigned short ushort_t;

static __device__ __forceinline__ float bf2f(ushort_t u) {
    return __uint_as_float(((unsigned int)u) << 16);
}
static __device__ __forceinline__ unsigned int f2bf_u(float f) {
    unsigned int x = __float_as_uint(f);
    unsigned int lsb = (x >> 16) & 1u;
    x += 0x7fffu + lsb;  // round-to-nearest-even
    return x >> 16;
}
static __device__ __forceinline__ ushort_t f2bf(float f) { return (ushort_t)f2bf_u(f); }

// ---- pass A: bucket histogram (LDS-aggregated) ----
__global__ void bucket_hist_kernel(const int* __restrict__ col, int* __restrict__ bucketCnt) {
    __shared__ int h[NBUCK];
    for (int t = threadIdx.x; t < NBUCK; t += 256) h[t] = 0;
    __syncthreads();
    for (int e = blockIdx.x * 256 + threadIdx.x; e < N_EDGES; e += gridDim.x * 256)
        atomicAdd(&h[col[e] >> 8], 1);
    __syncthreads();
    for (int t = threadIdx.x; t < NBUCK; t += 256)
        if (h[t]) atomicAdd(&bucketCnt[t], h[t]);
}

// ---- pass B: scan bucket counts -> bucketOff; init bcursor ----
__global__ void bucket_scan_kernel(const int* __restrict__ bucketCnt, int* __restrict__ bucketOff,
                                   int* __restrict__ bcursor) {
    __shared__ int tmp[512];
    int tx = threadIdx.x;
    int v = (tx < NBUCK) ? bucketCnt[tx] : 0;
    tmp[tx] = v;
    __syncthreads();
    for (int off = 1; off < 512; off <<= 1) {
        int t = (tx >= off) ? tmp[tx - off] : 0;
        __syncthreads();
        if (tx >= off) tmp[tx] += t;
        __syncthreads();
    }
    if (tx < NBUCK) {
        int o = tmp[tx] - v;
        bucketOff[tx] = o;
        bcursor[tx] = o;
    }
}

// ---- pass C: bin edges by bucket (block-aggregated append) ----
__global__ void bin_kernel(const int* __restrict__ row, const int* __restrict__ col,
                           int* __restrict__ bcursor, int2* __restrict__ tmpE) {
    __shared__ int hist[NBUCK];
    __shared__ int chunkOff[NBUCK];
    int tx = threadIdx.x;
    for (int t = tx; t < NBUCK; t += 512) hist[t] = 0;
    __syncthreads();
    int base = blockIdx.x * 4096;
    int myc[8], myr[8], myrank[8];
#pragma unroll 8
    for (int k = 0; k < 8; ++k) {
        int idx = base + k * 512 + tx;
        bool valid = idx < N_EDGES;
        int c = valid ? col[idx] : 0;
        int r = valid ? row[idx] : 0;
        myc[k] = c;
        myr[k] = r;
        myrank[k] = valid ? atomicAdd(&hist[c >> 8], 1) : 0;
    }
    __syncthreads();
    for (int t = tx; t < NBUCK; t += 512) {
        int hv = hist[t];
        chunkOff[t] = hv ? atomicAdd(&bcursor[t], hv) : 0;
    }
    __syncthreads();
#pragma unroll 8
    for (int k = 0; k < 8; ++k) {
        int idx = base + k * 512 + tx;
        if (idx < N_EDGES) {
            int pos = chunkOff[myc[k] >> 8] + myrank[k];
            tmpE[pos] = make_int2(myr[k], myc[k]);
        }
    }
}

// ---- pass D: per-bucket CSR: starts, isq, edgeRow; + npos reduction ----
__global__ void csr_kernel(const int2* __restrict__ tmpE, const int* __restrict__ bucketOff,
                           const int* __restrict__ bucketCnt, int* __restrict__ starts,
                           int* __restrict__ edgeRow, float* __restrict__ isq,
                           const float* __restrict__ labels, float* __restrict__ npos) {
    __shared__ int scnt[NPB];
    __shared__ int sscan[NPB];
    __shared__ int scur[NPB];
    __shared__ float red[NPB];
    int b = blockIdx.x;
    int lo = b * NPB;
    int nn = N_NODES - lo;
    if (nn > NPB) nn = NPB;
    int base = bucketOff[b];
    int ecnt = bucketCnt[b];
    int tx = threadIdx.x;
    scnt[tx] = 0;
    __syncthreads();
    for (int t = tx; t < ecnt; t += NPB) atomicAdd(&scnt[tmpE[base + t].y - lo], 1);
    __syncthreads();
    int v = scnt[tx];
    sscan[tx] = v;
    __syncthreads();
    for (int off = 1; off < NPB; off <<= 1) {
        int t = (tx >= off) ? sscan[tx - off] : 0;
        __syncthreads();
        if (tx >= off) sscan[tx] += t;
        __syncthreads();
    }
    int excl = sscan[tx] - v;
    scur[tx] = excl;
    float lab = 0.0f;
    if (tx < nn) {
        starts[lo + tx] = base + excl;
        isq[lo + tx] = rsqrtf((float)v + 1.0f);
        lab = labels[lo + tx];
    }
    if (b == NBUCK - 1 && tx == 0) starts[N_NODES] = N_EDGES;
    red[tx] = lab;
    __syncthreads();
    for (int s = NPB / 2; s > 0; s >>= 1) {
        if (tx < s) red[tx] += red[tx + s];
        __syncthreads();
    }
    if (tx == 0) atomicAdd(npos, red[0]);
    for (int t = tx; t < ecnt; t += NPB) {
        int2 rc = tmpE[base + t];
        int p = atomicAdd(&scur[rc.y - lo], 1);
        edgeRow[base + p] = rc.x;
    }
}

// ---- x (fp32 N*32) -> bf16 table PRE-SCALED by isq[node] ----
__global__ void xcast_kernel(const float* __restrict__ x, const float* __restrict__ isq,
                             ushort_t* __restrict__ xs) {
    int i = blockIdx.x * 256 + threadIdx.x;  // group of 4 floats; node = i>>3
    if (i < (N_NODES * 32) / 4) {
        float s = isq[i >> 3];
        float4 v = ((const float4*)x)[i];
        ushort4 o;
        o.x = f2bf(v.x * s); o.y = f2bf(v.y * s); o.z = f2bf(v.z * s); o.w = f2bf(v.w * s);
        ((ushort4*)xs)[i] = o;
    }
}

// ---- pack W1/W2/W3 into per-lane bf16x2 column tables ----
__global__ void wpack_kernel(const float* __restrict__ W1, const float* __restrict__ W2,
                             const float* __restrict__ W3, unsigned int* __restrict__ wp) {
    int t = blockIdx.x * 256 + threadIdx.x;
    if (t >= 80 * 64) return;
    int k2 = t >> 6, l = t & 63;
    const float* W;
    int kk;
    if (k2 < 16) { W = W1; kk = k2; }
    else if (k2 < 48) { W = W2; kk = k2 - 16; }
    else { W = W3; kk = k2 - 48; }
    float lo = W[(2 * kk) * 64 + l];
    float hi = W[(2 * kk + 1) * 64 + l];
    wp[t] = (f2bf_u(hi) << 16) | f2bf_u(lo);
}

// ---- layer 1 fused: agg(xs)[32] -> @W[32x64]+b -> relu -> bf16 hs (scaled) ----
// software-pipelined gathers: group g+1's 16 loads issue before group g's FMAs
__global__ void fused32_kernel(const int* __restrict__ starts, const int* __restrict__ edgeRow,
                               const ushort_t* __restrict__ xs, const float* __restrict__ isq,
                               const unsigned int* __restrict__ wpG,
                               const float* __restrict__ bias, ushort_t* __restrict__ hout) {
    __shared__ float sAgg[4][32];
    int w = threadIdx.x >> 6;
    int lane = threadIdx.x & 63;
    int f = lane & 31, half = lane >> 5;
    unsigned int wpk[16];
#pragma unroll
    for (int k2 = 0; k2 < 16; ++k2) wpk[k2] = wpG[k2 * 64 + lane];
    float bias_r = bias[lane];
    int nodeBase = blockIdx.x * (4 * NPW) + w * NPW;
    for (int i = 0; i < NPW; ++i) {
        int node = __builtin_amdgcn_readfirstlane(nodeBase + i);
        int sU = starts[node];
        int eU = starts[node + 1];
        float sic = isq[node];
        float acc[4] = {0.0f, 0.0f, 0.0f, 0.0f};
        int ngrp = (eU - sU + 15) >> 4;
        int jb = sU;
        int rowsA[16];
        unsigned int vvA[16];
#pragma unroll
        for (int q = 0; q < 16; ++q) {
            int idx = jb + q;
            rowsA[q] = edgeRow[idx < eU ? idx : sU];  // uniform clamp (SALU)
        }
#pragma unroll
        for (int q = 0; q < 16; ++q) vvA[q] = xs[(rowsA[q] << 5) + f];
        for (int g = 0; g < ngrp; ++g) {
            int rowsB[16];
            unsigned int vvB[16];
#pragma unroll
            for (int q = 0; q < 16; ++q) {
                int idx = jb + 16 + q;
                rowsB[q] = edgeRow[idx < eU ? idx : sU];  // uniform clamp -> L2-hot dup
            }
#pragma unroll
            for (int q = 0; q < 16; ++q) vvB[q] = xs[(rowsB[q] << 5) + f];  // prefetch
#pragma unroll
            for (int q = 0; q < 16; ++q) {
                float n = (jb + q < eU) ? 1.0f : 0.0f;  // SALU mask
                acc[q & 3] = fmaf(bf2f((ushort_t)vvA[q]), n, acc[q & 3]);
            }
#pragma unroll
            for (int q = 0; q < 16; ++q) vvA[q] = vvB[q];
            jb += 16;
        }
        float accsum = (acc[0] + acc[1]) + (acc[2] + acc[3]);  // halves identical
        if (half == 0) {
            accsum += bf2f(xs[(node << 5) + f]);       // self-loop (xs has isq folded)
            sAgg[w][f] = accsum * sic;                 // * isq[col] hoisted
        }
        float o = bias_r;
#pragma unroll
        for (int q = 0; q < 8; ++q) {  // 32-dot: 8x b128 broadcast + packed W regs
            float4 av = *(const float4*)&sAgg[w][q * 4];
            unsigned int p0 = wpk[2 * q], p1 = wpk[2 * q + 1];
            o = fmaf(av.x, __uint_as_float(p0 << 16), o);
            o = fmaf(av.y, __uint_as_float(p0 & 0xffff0000u), o);
            o = fmaf(av.z, __uint_as_float(p1 << 16), o);
            o = fmaf(av.w, __uint_as_float(p1 & 0xffff0000u), o);
        }
        o = o > 0.0f ? o : 0.0f;
        hout[(node << 6) + lane] = f2bf(o * sic);  // write SCALED for next layer's gather
    }
}

// ---- layers 2/3 fused: agg(hs)[64] -> @W[64x64]+b -> relu -> bf16 out ----
// software-pipelined gathers (32 in flight); outScaled selects hs vs h output
__global__ void fused64_kernel(const int* __restrict__ starts, const int* __restrict__ edgeRow,
                               const ushort_t* __restrict__ hs, const float* __restrict__ isq,
                               const unsigned int* __restrict__ wpG,
                               const float* __restrict__ bias, ushort_t* __restrict__ hout,
                               int outScaled) {
    __shared__ float sAgg[4][64];
    int w = threadIdx.x >> 6;
    int lane = threadIdx.x & 63;
    unsigned int wpk[32];
#pragma unroll
    for (int k2 = 0; k2 < 32; ++k2) wpk[k2] = wpG[k2 * 64 + lane];
    float bias_r = bias[lane];
    int nodeBase = blockIdx.x * (4 * NPW) + w * NPW;
    for (int i = 0; i < NPW; ++i) {
        int node = __builtin_amdgcn_readfirstlane(nodeBase + i);
        int sU = starts[node];
        int eU = starts[node + 1];
        float sic = isq[node];
        float acc[4];
        acc[0] = bf2f(hs[(node << 6) + lane]);  // self-loop (hs has isq[node] folded)
        acc[1] = 0.0f; acc[2] = 0.0f; acc[3] = 0.0f;
        int ngrp = (eU - sU + 15) >> 4;
        int jb = sU;
        int rowsA[16];
        unsigned int vvA[16];
#pragma unroll
        for (int q = 0; q < 16; ++q) {
            int idx = jb + q;
            rowsA[q] = edgeRow[idx < eU ? idx : sU];  // uniform clamp (SALU)
        }
#pragma unroll
        for (int q = 0; q < 16; ++q) vvA[q] = hs[(rowsA[q] << 6) + lane];
        for (int g = 0; g < ngrp; ++g) {
            int rowsB[16];
            unsigned int vvB[16];
#pragma unroll
            for (int q = 0; q < 16; ++q) {
                int idx = jb + 16 + q;
                rowsB[q] = edgeRow[idx < eU ? idx : sU];  // uniform clamp -> L2-hot dup
            }
#pragma unroll
            for (int q = 0; q < 16; ++q) vvB[q] = hs[(rowsB[q] << 6) + lane];  // prefetch
#pragma unroll
            for (int q = 0; q < 16; ++q) {
                float n = (jb + q < eU) ? 1.0f : 0.0f;  // SALU mask
                acc[q & 3] = fmaf(bf2f((ushort_t)vvA[q]), n, acc[q & 3]);
            }
#pragma unroll
            for (int q = 0; q < 16; ++q) vvA[q] = vvB[q];
            jb += 16;
        }
        sAgg[w][lane] = ((acc[0] + acc[1]) + (acc[2] + acc[3])) * sic;  // *isq[col] hoisted
        float o = bias_r;
#pragma unroll
        for (int q = 0; q < 16; ++q) {  // 64-dot: 16x b128 broadcast + packed W regs
            float4 av = *(const float4*)&sAgg[w][q * 4];
            unsigned int p0 = wpk[2 * q], p1 = wpk[2 * q + 1];
            o = fmaf(av.x, __uint_as_float(p0 << 16), o);
            o = fmaf(av.y, __uint_as_float(p0 & 0xffff0000u), o);
            o = fmaf(av.z, __uint_as_float(p1 << 16), o);
            o = fmaf(av.w, __uint_as_float(p1 & 0xffff0000u), o);
        }
        o = o > 0.0f ? o : 0.0f;
        float scale = outScaled ? sic : 1.0f;
        hout[(node << 6) + lane] = f2bf(o * scale);
    }
}

// ---- head: relu(h@Wl1+bl1)@Wl2+bl2 -> sigmoid -> p; weighted BCE -> loss ----
__global__ void head_kernel(const ushort_t* __restrict__ h, const float* __restrict__ Wl1,
                            const float* __restrict__ bl1, const float* __restrict__ Wl2,
                            const float* __restrict__ bl2, const float* __restrict__ labels,
                            const float* __restrict__ npos, float* __restrict__ out) {
    __shared__ float sW1[64 * 8];
    __shared__ float sb1[8];
    __shared__ float sW2[8];
    for (int t = threadIdx.x; t < 512; t += 256) sW1[t] = Wl1[t];
    if (threadIdx.x < 8) {
        sb1[threadIdx.x] = bl1[threadIdx.x];
        sW2[threadIdx.x] = Wl2[threadIdx.x];
    }
    __syncthreads();
    int i = blockIdx.x * 256 + threadIdx.x;
    float contrib = 0.0f;
    if (i < N_NODES) {
        const ushort4* hr4 = (const ushort4*)(h + (size_t)i * 64);
        float a[8];
#pragma unroll
        for (int j = 0; j < 8; ++j) a[j] = sb1[j];
#pragma unroll
        for (int kb = 0; kb < 16; ++kb) {
            ushort4 v4 = hr4[kb];
            float h0 = bf2f(v4.x), h1 = bf2f(v4.y), h2 = bf2f(v4.z), h3 = bf2f(v4.w);
#pragma unroll
            for (int j = 0; j < 8; ++j) {
                a[j] = fmaf(h0, sW1[(kb * 4 + 0) * 8 + j], a[j]);
                a[j] = fmaf(h1, sW1[(kb * 4 + 1) * 8 + j], a[j]);
                a[j] = fmaf(h2, sW1[(kb * 4 + 2) * 8 + j], a[j]);
                a[j] = fmaf(h3, sW1[(kb * 4 + 3) * 8 + j], a[j]);
            }
        }
        float z = bl2[0];
#pragma unroll
        for (int j = 0; j < 8; ++j) {
            float r = a[j] > 0.0f ? a[j] : 0.0f;
            z = fmaf(r, sW2[j], z);
        }
        float p = 1.0f / (1.0f + expf(-z));
        out[1 + i] = p;
        float y = labels[i];
        float np = *npos;
        float fn = (float)N_NODES;
        float wpos = fn / (2.0f * np);
        float wneg = fn / (2.0f * (fn - np));
        float wgt = y * wpos + (1.0f - y) * wneg;
        float lse = log1pf(expf(-fabsf(z)));
        float ls_pos = fminf(z, 0.0f) - lse;
        float ls_neg = fminf(-z, 0.0f) - lse;
        float bce = -(y * ls_pos + (1.0f - y) * ls_neg);
        contrib = wgt * bce / fn;
    }
    __shared__ float red[256];
    red[threadIdx.x] = contrib;
    __syncthreads();
    for (int s = 128; s > 0; s >>= 1) {
        if (threadIdx.x < s) red[threadIdx.x] += red[threadIdx.x + s];
        __syncthreads();
    }
    if (threadIdx.x == 0) atomicAdd(out, red[0]);
}

extern "C" void kernel_launch(void* const* d_in, const int* in_sizes, int n_in,
                              void* d_out, int out_size, void* d_ws, size_t ws_size,
                              hipStream_t stream) {
    const float* x      = (const float*)d_in[0];
    const int*   ei     = (const int*)d_in[1];
    const float* labels = (const float*)d_in[2];
    const float* W1  = (const float*)d_in[3];
    const float* b1  = (const float*)d_in[4];
    const float* W2  = (const float*)d_in[5];
    const float* b2  = (const float*)d_in[6];
    const float* W3  = (const float*)d_in[7];
    const float* b3  = (const float*)d_in[8];
    const float* Wl1 = (const float*)d_in[9];
    const float* bl1 = (const float*)d_in[10];
    const float* Wl2 = (const float*)d_in[11];
    const float* bl2 = (const float*)d_in[12];

    const int* row = ei;            // edge_index[0]
    const int* col = ei + N_EDGES;  // edge_index[1]
    float* out = (float*)d_out;

    // ---- workspace layout ----
    char* w = (char*)d_ws;
    int2*     tmpE    = (int2*)w;                               // E*8B
    int*      edgeRow = (int*)(w + (size_t)N_EDGES * 8);        // (E+32)*4B (pad for prefetch)
    ushort_t* xbf     = (ushort_t*)(edgeRow + N_EDGES + 32);    // N*32*2B (scaled)
    ushort_t* hbfA    = xbf + (size_t)N_NODES * 32;             // N*64*2B
    ushort_t* hbfB    = hbfA + (size_t)N_NODES * 64;            // N*64*2B
    int*      starts  = (int*)(hbfB + (size_t)N_NODES * 64);    // N+1
    int*      bucketCnt = starts + (N_NODES + 1);               // NBUCK
    int*      bucketOff = bucketCnt + NBUCK;                    // NBUCK
    int*      bcursor   = bucketOff + NBUCK;                    // NBUCK
    float*    isq  = (float*)(bcursor + NBUCK);                 // N
    float*    npos = isq + N_NODES;                             // 1
    unsigned int* wpG = (unsigned int*)(npos + 1);              // 80*64 u32

    hipMemsetAsync(bucketCnt, 0, NBUCK * sizeof(int), stream);
    hipMemsetAsync(npos, 0, sizeof(float), stream);
    hipMemsetAsync(out, 0, sizeof(float), stream);
    hipMemsetAsync(edgeRow + N_EDGES, 0, 32 * sizeof(int), stream);  // over-read slack

    const int FB = N_NODES / (4 * NPW);      // 6250 (fused blocks)
    const int BB = (N_EDGES + 4095) / 4096;  // 782
    const int XB = (N_NODES * 32 / 4 + 255) / 256;

    bucket_hist_kernel<<<1024, 256, 0, stream>>>(col, bucketCnt);
    bucket_scan_kernel<<<1, 512, 0, stream>>>(bucketCnt, bucketOff, bcursor);
    bin_kernel<<<BB, 512, 0, stream>>>(row, col, bcursor, tmpE);
    csr_kernel<<<NBUCK, NPB, 0, stream>>>(tmpE, bucketOff, bucketCnt, starts, edgeRow, isq,
                                          labels, npos);
    xcast_kernel<<<XB, 256, 0, stream>>>(x, isq, xbf);
    wpack_kernel<<<20, 256, 0, stream>>>(W1, W2, W3, wpG);

    fused32_kernel<<<FB, 256, 0, stream>>>(starts, edgeRow, xbf, isq, wpG, b1, hbfA);
    fused64_kernel<<<FB, 256, 0, stream>>>(starts, edgeRow, hbfA, isq, wpG + 16 * 64, b2,
                                           hbfB, 1);
    fused64_kernel<<<FB, 256, 0, stream>>>(starts, edgeRow, hbfB, isq, wpG + 48 * 64, b3,
                                           hbfA, 0);

    head_kernel<<<(N_NODES + 255) / 256, 256, 0, stream>>>(hbfA, Wl1, bl1, Wl2, bl2, labels,
                                                           npos, out);
}

// Round 15
// 415.661 us; speedup vs baseline: 3.7009x; 1.2332x over previous
//
#include <hip/hip_runtime.h>
#include <math.h>

#define N_NODES 100000
#define N_EDGES 3200000
#define NPB 256                              // nodes per bucket
#define NBUCK ((N_NODES + NPB - 1) / NPB)    // 391
#define NPW 4                                // nodes per wave (fused kernels)
#define NSEG 8                               // row segments (row>>14), 2MB table slice each

typedef unsigned short ushort_t;

static __device__ __forceinline__ float bf2f(ushort_t u) {
    return __uint_as_float(((unsigned int)u) << 16);
}
static __device__ __forceinline__ unsigned int f2bf_u(float f) {
    unsigned int x = __float_as_uint(f);
    unsigned int lsb = (x >> 16) & 1u;
    x += 0x7fffu + lsb;  // round-to-nearest-even
    return x >> 16;
}
static __device__ __forceinline__ ushort_t f2bf(float f) { return (ushort_t)f2bf_u(f); }

// ---- pass A: bucket histogram (LDS-aggregated) ----
__global__ void bucket_hist_kernel(const int* __restrict__ col, int* __restrict__ bucketCnt) {
    __shared__ int h[NBUCK];
    for (int t = threadIdx.x; t < NBUCK; t += 256) h[t] = 0;
    __syncthreads();
    for (int e = blockIdx.x * 256 + threadIdx.x; e < N_EDGES; e += gridDim.x * 256)
        atomicAdd(&h[col[e] >> 8], 1);
    __syncthreads();
    for (int t = threadIdx.x; t < NBUCK; t += 256)
        if (h[t]) atomicAdd(&bucketCnt[t], h[t]);
}

// ---- pass B: scan bucket counts -> bucketOff; init bcursor ----
__global__ void bucket_scan_kernel(const int* __restrict__ bucketCnt, int* __restrict__ bucketOff,
                                   int* __restrict__ bcursor) {
    __shared__ int tmp[512];
    int tx = threadIdx.x;
    int v = (tx < NBUCK) ? bucketCnt[tx] : 0;
    tmp[tx] = v;
    __syncthreads();
    for (int off = 1; off < 512; off <<= 1) {
        int t = (tx >= off) ? tmp[tx - off] : 0;
        __syncthreads();
        if (tx >= off) tmp[tx] += t;
        __syncthreads();
    }
    if (tx < NBUCK) {
        int o = tmp[tx] - v;
        bucketOff[tx] = o;
        bcursor[tx] = o;
    }
}

// ---- pass C: bin edges by bucket; writes packed u32 {colLocal<<17 | row} ----
__global__ void bin_kernel(const int* __restrict__ row, const int* __restrict__ col,
                           int* __restrict__ bcursor, unsigned int* __restrict__ tmpE) {
    __shared__ int hist[NBUCK];
    __shared__ int chunkOff[NBUCK];
    int tx = threadIdx.x;
    for (int t = tx; t < NBUCK; t += 512) hist[t] = 0;
    __syncthreads();
    int base = blockIdx.x * 4096;
    int myc[8], myr[8], myrank[8];
#pragma unroll 8
    for (int k = 0; k < 8; ++k) {
        int idx = base + k * 512 + tx;
        bool valid = idx < N_EDGES;
        int c = valid ? col[idx] : 0;
        int r = valid ? row[idx] : 0;
        myc[k] = c;
        myr[k] = r;
        myrank[k] = valid ? atomicAdd(&hist[c >> 8], 1) : 0;
    }
    __syncthreads();
    for (int t = tx; t < NBUCK; t += 512) {
        int hv = hist[t];
        chunkOff[t] = hv ? atomicAdd(&bcursor[t], hv) : 0;
    }
    __syncthreads();
#pragma unroll 8
    for (int k = 0; k < 8; ++k) {
        int idx = base + k * 512 + tx;
        if (idx < N_EDGES) {
            int pos = chunkOff[myc[k] >> 8] + myrank[k];
            tmpE[pos] = (unsigned int)myr[k] | ((unsigned int)(myc[k] & 255) << 17);
        }
    }
}

// ---- pass D: per-bucket CSR ordered by (node, rowSegment): starts, isq, edgeRow ----
__global__ void csr_kernel(const unsigned int* __restrict__ tmpE, const int* __restrict__ bucketOff,
                           const int* __restrict__ bucketCnt, int* __restrict__ starts,
                           int* __restrict__ edgeRow, float* __restrict__ isq,
                           const float* __restrict__ labels, float* __restrict__ npos) {
    __shared__ int scnt[NPB * NSEG];  // counts -> cursors, 8KB
    __shared__ int tsum[NPB];
    __shared__ float red[NPB];
    int b = blockIdx.x;
    int lo = b * NPB;
    int nn = N_NODES - lo;
    if (nn > NPB) nn = NPB;
    int base = bucketOff[b];
    int ecnt = bucketCnt[b];
    int tx = threadIdx.x;
    for (int t = tx; t < NPB * NSEG; t += NPB) scnt[t] = 0;
    __syncthreads();
    for (int t = tx; t < ecnt; t += NPB) {
        unsigned int v = tmpE[base + t];
        int r = v & 0x1FFFF;
        int cl = v >> 17;
        atomicAdd(&scnt[cl * NSEG + (r >> 14)], 1);
    }
    __syncthreads();
    // thread tx owns node tx: serial scan of its NSEG counts
    int my[NSEG];
    int deg = 0;
#pragma unroll
    for (int s = 0; s < NSEG; ++s) {
        my[s] = scnt[tx * NSEG + s];
        deg += my[s];
    }
    tsum[tx] = deg;
    __syncthreads();
    int v = tsum[tx];
    for (int off = 1; off < NPB; off <<= 1) {
        int t = (tx >= off) ? tsum[tx - off] : 0;
        __syncthreads();
        if (tx >= off) tsum[tx] += t;
        __syncthreads();
    }
    int nodeOff = tsum[tx] - v;  // exclusive prefix within bucket
    int run = nodeOff;
#pragma unroll
    for (int s = 0; s < NSEG; ++s) {  // write per-(node,seg) cursors
        scnt[tx * NSEG + s] = run;
        run += my[s];
    }
    float lab = 0.0f;
    if (tx < nn) {
        starts[lo + tx] = base + nodeOff;
        isq[lo + tx] = rsqrtf((float)deg + 1.0f);
        lab = labels[lo + tx];
    }
    if (b == NBUCK - 1 && tx == 0) starts[N_NODES] = N_EDGES;
    red[tx] = lab;
    __syncthreads();
    for (int s = NPB / 2; s > 0; s >>= 1) {
        if (tx < s) red[tx] += red[tx + s];
        __syncthreads();
    }
    if (tx == 0) atomicAdd(npos, red[0]);
    __syncthreads();
    for (int t = tx; t < ecnt; t += NPB) {
        unsigned int v2 = tmpE[base + t];
        int r = v2 & 0x1FFFF;
        int cl = v2 >> 17;
        int p = atomicAdd(&scnt[cl * NSEG + (r >> 14)], 1);
        edgeRow[base + p] = r;
    }
}

// ---- x (fp32 N*32) -> bf16 table PRE-SCALED by isq[node] ----
__global__ void xcast_kernel(const float* __restrict__ x, const float* __restrict__ isq,
                             ushort_t* __restrict__ xs) {
    int i = blockIdx.x * 256 + threadIdx.x;  // group of 4 floats; node = i>>3
    if (i < (N_NODES * 32) / 4) {
        float s = isq[i >> 3];
        float4 v = ((const float4*)x)[i];
        ushort4 o;
        o.x = f2bf(v.x * s); o.y = f2bf(v.y * s); o.z = f2bf(v.z * s); o.w = f2bf(v.w * s);
        ((ushort4*)xs)[i] = o;
    }
}

// ---- pack W1/W2/W3 into per-lane bf16x2 column tables ----
__global__ void wpack_kernel(const float* __restrict__ W1, const float* __restrict__ W2,
                             const float* __restrict__ W3, unsigned int* __restrict__ wp) {
    int t = blockIdx.x * 256 + threadIdx.x;
    if (t >= 80 * 64) return;
    int k2 = t >> 6, l = t & 63;
    const float* W;
    int kk;
    if (k2 < 16) { W = W1; kk = k2; }
    else if (k2 < 48) { W = W2; kk = k2 - 16; }
    else { W = W3; kk = k2 - 48; }
    float lo = W[(2 * kk) * 64 + l];
    float hi = W[(2 * kk + 1) * 64 + l];
    wp[t] = (f2bf_u(hi) << 16) | f2bf_u(lo);
}

// ---- layer 1 fused: agg(xs)[32] -> @W[32x64]+b -> relu -> bf16 hs (scaled) ----
__global__ void fused32_kernel(const int* __restrict__ starts, const int* __restrict__ edgeRow,
                               const ushort_t* __restrict__ xs, const float* __restrict__ isq,
                               const unsigned int* __restrict__ wpG,
                               const float* __restrict__ bias, ushort_t* __restrict__ hout) {
    __shared__ float sAgg[4][32];
    int w = threadIdx.x >> 6;
    int lane = threadIdx.x & 63;
    int f = lane & 31, half = lane >> 5;
    unsigned int wpk[16];
#pragma unroll
    for (int k2 = 0; k2 < 16; ++k2) wpk[k2] = wpG[k2 * 64 + lane];
    float bias_r = bias[lane];
    int nodeBase = blockIdx.x * (4 * NPW) + w * NPW;
    for (int i = 0; i < NPW; ++i) {
        int node = __builtin_amdgcn_readfirstlane(nodeBase + i);
        int sU = starts[node];
        int eU = starts[node + 1];
        float sic = isq[node];
        float acc[4] = {0.0f, 0.0f, 0.0f, 0.0f};
        int ngrp = (eU - sU + 15) >> 4;
        int jb = sU;
        for (int g = 0; g < ngrp; ++g) {
            int rows[16];
#pragma unroll
            for (int q = 0; q < 16; ++q) rows[q] = edgeRow[jb + q];  // uniform -> s_load
            unsigned int vv[16];
#pragma unroll
            for (int q = 0; q < 16; ++q) vv[q] = xs[(rows[q] << 5) + f];  // 16 in flight
#pragma unroll
            for (int q = 0; q < 16; ++q) {
                float n = (jb + q < eU) ? 1.0f : 0.0f;  // SALU mask
                acc[q & 3] = fmaf(bf2f((ushort_t)vv[q]), n, acc[q & 3]);
            }
            jb += 16;
        }
        float accsum = (acc[0] + acc[1]) + (acc[2] + acc[3]);  // halves identical
        if (half == 0) {
            accsum += bf2f(xs[(node << 5) + f]);       // self-loop (xs has isq folded)
            sAgg[w][f] = accsum * sic;                 // * isq[col] hoisted
        }
        float o = bias_r;
#pragma unroll
        for (int q = 0; q < 8; ++q) {  // 32-dot: 8x b128 broadcast + packed W regs
            float4 av = *(const float4*)&sAgg[w][q * 4];
            unsigned int p0 = wpk[2 * q], p1 = wpk[2 * q + 1];
            o = fmaf(av.x, __uint_as_float(p0 << 16), o);
            o = fmaf(av.y, __uint_as_float(p0 & 0xffff0000u), o);
            o = fmaf(av.z, __uint_as_float(p1 << 16), o);
            o = fmaf(av.w, __uint_as_float(p1 & 0xffff0000u), o);
        }
        o = o > 0.0f ? o : 0.0f;
        hout[(node << 6) + lane] = f2bf(o * sic);  // write SCALED for next layer's gather
    }
}

// ---- layers 2/3 fused: agg(hs)[64] -> @W[64x64]+b -> relu -> bf16 out ----
__global__ void fused64_kernel(const int* __restrict__ starts, const int* __restrict__ edgeRow,
                               const ushort_t* __restrict__ hs, const float* __restrict__ isq,
                               const unsigned int* __restrict__ wpG,
                               const float* __restrict__ bias, ushort_t* __restrict__ hout,
                               int outScaled) {
    __shared__ float sAgg[4][64];
    int w = threadIdx.x >> 6;
    int lane = threadIdx.x & 63;
    unsigned int wpk[32];
#pragma unroll
    for (int k2 = 0; k2 < 32; ++k2) wpk[k2] = wpG[k2 * 64 + lane];
    float bias_r = bias[lane];
    int nodeBase = blockIdx.x * (4 * NPW) + w * NPW;
    for (int i = 0; i < NPW; ++i) {
        int node = __builtin_amdgcn_readfirstlane(nodeBase + i);
        int sU = starts[node];
        int eU = starts[node + 1];
        float sic = isq[node];
        float acc[4];
        acc[0] = bf2f(hs[(node << 6) + lane]);  // self-loop (hs has isq[node] folded)
        acc[1] = 0.0f; acc[2] = 0.0f; acc[3] = 0.0f;
        int ngrp = (eU - sU + 15) >> 4;
        int jb = sU;
        for (int g = 0; g < ngrp; ++g) {
            int rows[16];
#pragma unroll
            for (int q = 0; q < 16; ++q) rows[q] = edgeRow[jb + q];  // uniform -> s_load
            unsigned int vv[16];
#pragma unroll
            for (int q = 0; q < 16; ++q) vv[q] = hs[(rows[q] << 6) + lane];  // 16 in flight
#pragma unroll
            for (int q = 0; q < 16; ++q) {
                float n = (jb + q < eU) ? 1.0f : 0.0f;  // SALU mask
                acc[q & 3] = fmaf(bf2f((ushort_t)vv[q]), n, acc[q & 3]);
            }
            jb += 16;
        }
        sAgg[w][lane] = ((acc[0] + acc[1]) + (acc[2] + acc[3])) * sic;  // *isq[col] hoisted
        float o = bias_r;
#pragma unroll
        for (int q = 0; q < 16; ++q) {  // 64-dot: 16x b128 broadcast + packed W regs
            float4 av = *(const float4*)&sAgg[w][q * 4];
            unsigned int p0 = wpk[2 * q], p1 = wpk[2 * q + 1];
            o = fmaf(av.x, __uint_as_float(p0 << 16), o);
            o = fmaf(av.y, __uint_as_float(p0 & 0xffff0000u), o);
            o = fmaf(av.z, __uint_as_float(p1 << 16), o);
            o = fmaf(av.w, __uint_as_float(p1 & 0xffff0000u), o);
        }
        o = o > 0.0f ? o : 0.0f;
        float scale = outScaled ? sic : 1.0f;
        hout[(node << 6) + lane] = f2bf(o * scale);
    }
}

// ---- head: relu(h@Wl1+bl1)@Wl2+bl2 -> sigmoid -> p; weighted BCE -> loss ----
__global__ void head_kernel(const ushort_t* __restrict__ h, const float* __restrict__ Wl1,
                            const float* __restrict__ bl1, const float* __restrict__ Wl2,
                            const float* __restrict__ bl2, const float* __restrict__ labels,
                            const float* __restrict__ npos, float* __restrict__ out) {
    __shared__ float sW1[64 * 8];
    __shared__ float sb1[8];
    __shared__ float sW2[8];
    for (int t = threadIdx.x; t < 512; t += 256) sW1[t] = Wl1[t];
    if (threadIdx.x < 8) {
        sb1[threadIdx.x] = bl1[threadIdx.x];
        sW2[threadIdx.x] = Wl2[threadIdx.x];
    }
    __syncthreads();
    int i = blockIdx.x * 256 + threadIdx.x;
    float contrib = 0.0f;
    if (i < N_NODES) {
        const ushort4* hr4 = (const ushort4*)(h + (size_t)i * 64);
        float a[8];
#pragma unroll
        for (int j = 0; j < 8; ++j) a[j] = sb1[j];
#pragma unroll
        for (int kb = 0; kb < 16; ++kb) {
            ushort4 v4 = hr4[kb];
            float h0 = bf2f(v4.x), h1 = bf2f(v4.y), h2 = bf2f(v4.z), h3 = bf2f(v4.w);
#pragma unroll
            for (int j = 0; j < 8; ++j) {
                a[j] = fmaf(h0, sW1[(kb * 4 + 0) * 8 + j], a[j]);
                a[j] = fmaf(h1, sW1[(kb * 4 + 1) * 8 + j], a[j]);
                a[j] = fmaf(h2, sW1[(kb * 4 + 2) * 8 + j], a[j]);
                a[j] = fmaf(h3, sW1[(kb * 4 + 3) * 8 + j], a[j]);
            }
        }
        float z = bl2[0];
#pragma unroll
        for (int j = 0; j < 8; ++j) {
            float r = a[j] > 0.0f ? a[j] : 0.0f;
            z = fmaf(r, sW2[j], z);
        }
        float p = 1.0f / (1.0f + expf(-z));
        out[1 + i] = p;
        float y = labels[i];
        float np = *npos;
        float fn = (float)N_NODES;
        float wpos = fn / (2.0f * np);
        float wneg = fn / (2.0f * (fn - np));
        float wgt = y * wpos + (1.0f - y) * wneg;
        float lse = log1pf(expf(-fabsf(z)));
        float ls_pos = fminf(z, 0.0f) - lse;
        float ls_neg = fminf(-z, 0.0f) - lse;
        float bce = -(y * ls_pos + (1.0f - y) * ls_neg);
        contrib = wgt * bce / fn;
    }
    __shared__ float red[256];
    red[threadIdx.x] = contrib;
    __syncthreads();
    for (int s = 128; s > 0; s >>= 1) {
        if (threadIdx.x < s) red[threadIdx.x] += red[threadIdx.x + s];
        __syncthreads();
    }
    if (threadIdx.x == 0) atomicAdd(out, red[0]);
}

extern "C" void kernel_launch(void* const* d_in, const int* in_sizes, int n_in,
                              void* d_out, int out_size, void* d_ws, size_t ws_size,
                              hipStream_t stream) {
    const float* x      = (const float*)d_in[0];
    const int*   ei     = (const int*)d_in[1];
    const float* labels = (const float*)d_in[2];
    const float* W1  = (const float*)d_in[3];
    const float* b1  = (const float*)d_in[4];
    const float* W2  = (const float*)d_in[5];
    const float* b2  = (const float*)d_in[6];
    const float* W3  = (const float*)d_in[7];
    const float* b3  = (const float*)d_in[8];
    const float* Wl1 = (const float*)d_in[9];
    const float* bl1 = (const float*)d_in[10];
    const float* Wl2 = (const float*)d_in[11];
    const float* bl2 = (const float*)d_in[12];

    const int* row = ei;            // edge_index[0]
    const int* col = ei + N_EDGES;  // edge_index[1]
    float* out = (float*)d_out;

    // ---- workspace layout ----
    char* w = (char*)d_ws;
    unsigned int* tmpE = (unsigned int*)w;                      // E*4B packed {cl<<17|row}
    int*      edgeRow = (int*)(w + (size_t)N_EDGES * 4);        // (E+16)*4B (pad)
    ushort_t* xbf     = (ushort_t*)(edgeRow + N_EDGES + 16);    // N*32*2B (scaled)
    ushort_t* hbfA    = xbf + (size_t)N_NODES * 32;             // N*64*2B
    ushort_t* hbfB    = hbfA + (size_t)N_NODES * 64;            // N*64*2B
    int*      starts  = (int*)(hbfB + (size_t)N_NODES * 64);    // N+1
    int*      bucketCnt = starts + (N_NODES + 1);               // NBUCK
    int*      bucketOff = bucketCnt + NBUCK;                    // NBUCK
    int*      bcursor   = bucketOff + NBUCK;                    // NBUCK
    float*    isq  = (float*)(bcursor + NBUCK);                 // N
    float*    npos = isq + N_NODES;                             // 1
    unsigned int* wpG = (unsigned int*)(npos + 1);              // 80*64 u32

    hipMemsetAsync(bucketCnt, 0, NBUCK * sizeof(int), stream);
    hipMemsetAsync(npos, 0, sizeof(float), stream);
    hipMemsetAsync(out, 0, sizeof(float), stream);
    hipMemsetAsync(edgeRow + N_EDGES, 0, 16 * sizeof(int), stream);  // over-read slack

    const int FB = N_NODES / (4 * NPW);      // 6250 (fused blocks)
    const int BB = (N_EDGES + 4095) / 4096;  // 782
    const int XB = (N_NODES * 32 / 4 + 255) / 256;

    bucket_hist_kernel<<<1024, 256, 0, stream>>>(col, bucketCnt);
    bucket_scan_kernel<<<1, 512, 0, stream>>>(bucketCnt, bucketOff, bcursor);
    bin_kernel<<<BB, 512, 0, stream>>>(row, col, bcursor, tmpE);
    csr_kernel<<<NBUCK, NPB, 0, stream>>>(tmpE, bucketOff, bucketCnt, starts, edgeRow, isq,
                                          labels, npos);
    xcast_kernel<<<XB, 256, 0, stream>>>(x, isq, xbf);
    wpack_kernel<<<20, 256, 0, stream>>>(W1, W2, W3, wpG);

    fused32_kernel<<<FB, 256, 0, stream>>>(starts, edgeRow, xbf, isq, wpG, b1, hbfA);
    fused64_kernel<<<FB, 256, 0, stream>>>(starts, edgeRow, hbfA, isq, wpG + 16 * 64, b2,
                                           hbfB, 1);
    fused64_kernel<<<FB, 256, 0, stream>>>(starts, edgeRow, hbfB, isq, wpG + 48 * 64, b3,
                                           hbfA, 0);

    head_kernel<<<(N_NODES + 255) / 256, 256, 0, stream>>>(hbfA, Wl1, bl1, Wl2, bl2, labels,
                                                           npos, out);
}